// Round 9
// baseline (176.114 us; speedup 1.0000x reference)
//
#include <hip/hip_runtime.h>
#include <math.h>

#define DECAY 0.8f
constexpr int B_     = 16;
constexpr int NSEQ   = 4096;
constexpr int D      = 64;
constexpr int C      = 4096;
constexpr int N      = B_ * NSEQ;       // 65536 rows
constexpr int NCHUNK = 4;               // code chunks (blockIdx.y)
constexpr int CCHUNK = C / NCHUNK;      // 1024 codes
constexpr int PANEL  = 32;              // codes per panel (dbuf: 16 KB LDS)
constexpr int NPANEL = CCHUNK / PANEL;  // 32

#define GATE_THR  3e-4f                  // >> 2x mfma-split err (~1e-4 at ||x||<=12)
#define CONS_THR  1e-3f                  // consistency: exact-vs-approx winner

typedef __attribute__((ext_vector_type(8))) short bf16x8;
typedef __attribute__((ext_vector_type(4))) float f32x4;

__device__ __forceinline__ unsigned short bf16_rn(float f) {
    unsigned u = __builtin_bit_cast(unsigned, f);
    u += 0x7FFFu + ((u >> 16) & 1u);
    return (unsigned short)(u >> 16);
}
__device__ __forceinline__ float bf16_to_f(unsigned short h) {
    unsigned u = ((unsigned)h) << 16;
    return __builtin_bit_cast(float, u);
}
__device__ __forceinline__ f32x4 mfma16(bf16x8 a, bf16x8 b, f32x4 c) {
    return __builtin_amdgcn_mfma_f32_16x16x32_bf16(a, b, c, 0, 0, 0);
}
__device__ __forceinline__ void gload_lds16(const unsigned short* g,
                                            unsigned short* l) {
    __builtin_amdgcn_global_load_lds(
        (const __attribute__((address_space(1))) unsigned int*)g,
        (__attribute__((address_space(3))) unsigned int*)l, 16, 0, 0);
}

// ---------------------------------------------------------------------------
// Kernel 1: embed_n = l2norm(embed) (f32), bf16 hi/lo split in the
// XOR-swizzled LDS-image layout (granule g of code row at g^(code&7)).
// Zeroes embed_sum / bins / dirty_count.
// ---------------------------------------------------------------------------
__global__ __launch_bounds__(256) void prep_e_kernel(
    const float* __restrict__ embed,
    float* __restrict__ embed_n,
    unsigned short* __restrict__ e_hi,
    unsigned short* __restrict__ e_lo,
    float* __restrict__ embed_sum,
    float* __restrict__ bins,
    int* __restrict__ dirty_count)
{
    int code = blockIdx.x * 4 + (threadIdx.x >> 6);
    int lane = threadIdx.x & 63;
    float v = embed[code * D + lane];
    float ss = v * v;
    #pragma unroll
    for (int o = 32; o > 0; o >>= 1) ss += __shfl_xor(ss, o);
    float inv = 1.0f / fmaxf(sqrtf(ss), 1e-12f);
    float en = v * inv;
    embed_n[code * D + lane] = en;

    unsigned short hi = bf16_rn(en);
    unsigned short lo = bf16_rn(en - bf16_to_f(hi));
    int g   = lane >> 3;                               // 16B granule 0..7
    int pos = code * D + ((g ^ (code & 7)) << 3) + (lane & 7);
    e_hi[pos] = hi;
    e_lo[pos] = lo;

    embed_sum[code * D + lane] = 0.0f;
    if (lane == 0) bins[code] = 0.0f;
    if (blockIdx.x == 0 && threadIdx.x == 0) *dirty_count = 0;
}

// ---------------------------------------------------------------------------
// Kernel 2: MFMA partial argmax over a 1024-code chunk (blockIdx.y of 4).
// 2048 blocks = 8 blocks/CU, 32 waves/CU; LDS 16 KB/block (double-buffered
// 32-code panels). 2-PHASE PIPELINE (T3/T4 minimum recipe):
//   vmcnt(0); s_barrier; issue global_load_lds(p+1)->buf^1; compute(p,buf)
// Issue sits after the barrier closing compute(p-1) => no WAR race on buf^1;
// loads(p+1) stay in flight across compute(p); vmcnt(0) at the next iter top
// waits loads that had a full compute phase to land. Raw s_barrier (not
// __syncthreads) to avoid the forced full drain.
// Tile-granular top-2 bookkeeping (round-8, verified): quarter-tile max +
// wave-uniform tile id; exact winner recovered by merge_scatter's rescan.
// Partial (m1, tile, m2x, 0) -> the row's quantize slot (float4 at chunk*4).
// ---------------------------------------------------------------------------
__global__ __launch_bounds__(256) void assign_mfma_kernel(
    const float* __restrict__ x,
    const unsigned short* __restrict__ e_hi,
    const unsigned short* __restrict__ e_lo,
    float* __restrict__ part)               // == q_out region of d_out
{
    __shared__ unsigned short lds_hi[2][PANEL * D];   // 2 x 4 KB
    __shared__ unsigned short lds_lo[2][PANEL * D];   // 2 x 4 KB

    const int tid  = threadIdx.x;
    const int lane = tid & 63;
    const int wid  = tid >> 6;
    const int l15  = lane & 15;
    const int lg   = lane >> 4;                  // 0..3
    const int rb   = (blockIdx.x * 4 + wid) * 32;
    const int cy   = blockIdx.y;                 // code chunk 0..3

    // ---- x fragments (2 row-groups x 2 K-chunks), bf16 hi/lo split
    bf16x8 xhi[2][2], xlo[2][2];
    #pragma unroll
    for (int g = 0; g < 2; ++g) {
        #pragma unroll
        for (int c = 0; c < 2; ++c) {
            const float* p = x + (size_t)(rb + g * 16 + l15) * D + c * 32 + lg * 8;
            float4 t0 = *(const float4*)p;
            float4 t1 = *(const float4*)(p + 4);
            float e[8] = {t0.x, t0.y, t0.z, t0.w, t1.x, t1.y, t1.z, t1.w};
            bf16x8 h, l2;
            #pragma unroll
            for (int j = 0; j < 8; ++j) {
                unsigned short hh = bf16_rn(e[j]);
                h[j]  = (short)hh;
                l2[j] = (short)bf16_rn(e[j] - bf16_to_f(hh));
            }
            xhi[g][c] = h;
            xlo[g][c] = l2;
        }
    }

    // swizzled LDS read offsets; granule index = c*4+lg, s7 = l15&7
    const int s7   = l15 & 7;
    const int off0 = l15 * D + (((0 + lg) ^ s7) << 3);
    const int off1 = l15 * D + (((4 + lg) ^ s7) << 3);

    float m1[2] = {-3.4e38f, -3.4e38f};
    float m2[2] = {-3.4e38f, -3.4e38f};
    int   tl[2] = {0, 0};

    const size_t chunk_base = (size_t)cy * NPANEL * PANEL * D;

    // prologue: stage panel 0 into buf 0
    gload_lds16(e_hi + chunk_base + tid * 8, &lds_hi[0][tid * 8]);
    gload_lds16(e_lo + chunk_base + tid * 8, &lds_lo[0][tid * 8]);

    for (int p = 0; p < NPANEL; ++p) {           // 32 panels of 32 codes
        const int cur = p & 1;
        asm volatile("s_waitcnt vmcnt(0)" ::: "memory");
        __builtin_amdgcn_s_barrier();
        __builtin_amdgcn_sched_barrier(0);

        if (p + 1 < NPANEL) {                    // issue next panel -> buf^1
            const size_t nb = chunk_base + (size_t)(p + 1) * PANEL * D;
            gload_lds16(e_hi + nb + tid * 8, &lds_hi[cur ^ 1][tid * 8]);
            gload_lds16(e_lo + nb + tid * 8, &lds_lo[cur ^ 1][tid * 8]);
        }

        const unsigned short* Lh = lds_hi[cur];
        const unsigned short* Ll = lds_lo[cur];
        const int pp = cy * NPANEL + p;          // global panel id 0..127

        #pragma unroll
        for (int t = 0; t < PANEL / 16; ++t) {   // 2 code-tiles of 16
            bf16x8 eh0 = *(const bf16x8*)(Lh + t * 1024 + off0);
            bf16x8 eh1 = *(const bf16x8*)(Lh + t * 1024 + off1);
            bf16x8 el0 = *(const bf16x8*)(Ll + t * 1024 + off0);
            bf16x8 el1 = *(const bf16x8*)(Ll + t * 1024 + off1);
            const int pt = pp * 2 + t;           // global tile id 0..255
            #pragma unroll
            for (int g = 0; g < 2; ++g) {
                f32x4 acc = {0.f, 0.f, 0.f, 0.f};
                acc = mfma16(eh0, xhi[g][0], acc);
                acc = mfma16(eh1, xhi[g][1], acc);
                acc = mfma16(el0, xhi[g][0], acc);
                acc = mfma16(el1, xhi[g][1], acc);
                acc = mfma16(eh0, xlo[g][0], acc);
                acc = mfma16(eh1, xlo[g][1], acc);
                // quarter-tile max (this lane's 4 codes of the tile)
                float t1 = fmaxf(fmaxf(acc[0], acc[1]), fmaxf(acc[2], acc[3]));
                float mn = fminf(m1[g], t1);
                bool  gt = t1 > m1[g];
                tl[g] = gt ? pt : tl[g];         // wave-uniform source
                m1[g] = fmaxf(m1[g], t1);
                m2[g] = fmaxf(m2[g], mn);
            }
        }
    }

    // ---- merge lg quarters via shuffle; m2 = best outside winner quarter
    #pragma unroll
    for (int g = 0; g < 2; ++g) {
        float a1 = m1[g], a2 = m2[g];
        int   at = tl[g];
        #pragma unroll
        for (int d = 16; d <= 32; d <<= 1) {
            float b1 = __shfl_xor(a1, d);
            float b2 = __shfl_xor(a2, d);
            int   bt = __shfl_xor(at, d);
            float nm2 = fmaxf(fmaxf(a2, b2), fminf(a1, b1));
            bool  take = (b1 > a1);              // exact ties -> m2==m1 -> dirty
            a1 = take ? b1 : a1;
            at = take ? bt : at;
            a2 = nm2;
        }
        if (lane < 16) {
            int row = rb + g * 16 + lane;
            float4 pr;
            pr.x = a1; pr.y = (float)at; pr.z = a2; pr.w = 0.0f;
            *reinterpret_cast<float4*>(part + (size_t)row * D + cy * 4) = pr;
        }
    }
}

// ---------------------------------------------------------------------------
// Kernel 3: fused merge + exact tile rescan + scatter, one WAVE per row.
// (unchanged from round 8, verified absmax 0)
// ---------------------------------------------------------------------------
__global__ __launch_bounds__(256) void merge_scatter_kernel(
    const float* __restrict__ x,
    const float* __restrict__ embed,
    const float* __restrict__ embed_n,
    float* __restrict__ q_out,               // holds partials on entry
    float* __restrict__ ind_out,
    float* __restrict__ embed_sum,
    float* __restrict__ bins,
    int* __restrict__ dirty_count,
    int* __restrict__ dirty_list)
{
    int wid  = threadIdx.x >> 6;
    int lane = threadIdx.x & 63;
    int row  = blockIdx.x * 4 + wid;

    // ---- merge the 4 chunk partials (broadcast reads)
    float w1a, m2x; int wt;
    {
        const float4* pp = reinterpret_cast<const float4*>(q_out + (size_t)row * D);
        float4 P = pp[0];
        w1a = P.x; wt = (int)P.y; m2x = P.z;
        #pragma unroll
        for (int j = 1; j < NCHUNK; ++j) {
            float4 Q = pp[j];
            float nm2 = fmaxf(fmaxf(m2x, Q.z), fminf(w1a, Q.x));
            if (Q.x > w1a) { w1a = Q.x; wt = (int)Q.y; }
            m2x = nm2;
        }
    }

    // ---- exact fp32 rescan of the 16-code winner tile
    int   csub = lane >> 2;                  // code within tile 0..15
    int   code = wt * 16 + csub;
    float dot;
    {
        const float4* ep = (const float4*)(embed_n + (size_t)code * D + (lane & 3) * 16);
        const float4* xp = (const float4*)(x + (size_t)row * D + (lane & 3) * 16);
        float a0 = 0.f, a1 = 0.f, a2 = 0.f, a3 = 0.f;
        #pragma unroll
        for (int k = 0; k < 4; ++k) {
            float4 e = ep[k], xx = xp[k];
            a0 = fmaf(e.x, xx.x, a0);
            a1 = fmaf(e.y, xx.y, a1);
            a2 = fmaf(e.z, xx.z, a2);
            a3 = fmaf(e.w, xx.w, a3);
        }
        dot = (a0 + a1) + (a2 + a3);
        dot += __shfl_xor(dot, 1);
        dot += __shfl_xor(dot, 2);           // all 4 lanes of group hold full dot
    }
    // butterfly top-2 over the 16 distinct codes
    float v = dot, s = -3.4e38f;
    int   vi = code;
    #pragma unroll
    for (int d = 4; d <= 32; d <<= 1) {
        float bv = __shfl_xor(v, d);
        float bs = __shfl_xor(s, d);
        int   bi = __shfl_xor(vi, d);
        float ns = fmaxf(fmaxf(s, bs), fminf(v, bv));
        bool  take = (bv > v) || (bv == v && bi < vi);
        v  = take ? bv : v;
        vi = take ? bi : vi;
        s  = ns;
    }

    bool dirty = (v - m2x <= GATE_THR) || (fabsf(v - w1a) > CONS_THR);
    if (dirty) {
        if (lane == 0) {
            int slot = atomicAdd(dirty_count, 1);
            dirty_list[slot] = row;
        }
        return;
    }

    // ---- scatter (clean row)
    float xk = x[(size_t)row * D + lane];
    float ss = xk * xk;
    #pragma unroll
    for (int o = 32; o > 0; o >>= 1) ss += __shfl_xor(ss, o);
    float inv = 1.0f / fmaxf(sqrtf(ss), 1e-12f);

    if (lane == 0) {
        ind_out[row] = (float)vi;
        atomicAdd(&bins[vi], 1.0f);
    }
    q_out[(size_t)row * D + lane] = embed[(size_t)vi * D + lane];
    atomicAdd(&embed_sum[(size_t)vi * D + lane], xk * inv);
}

// ---------------------------------------------------------------------------
// Kernel 4: exact fp32 re-argmax for dirty rows + their deferred scatter.
// (unchanged from round 8, verified)
// ---------------------------------------------------------------------------
__global__ __launch_bounds__(256) void fallback_kernel(
    const float* __restrict__ x,
    const float* __restrict__ embed,
    const float* __restrict__ embed_n,
    const int* __restrict__ dirty_count,
    const int* __restrict__ dirty_list,
    float* __restrict__ ind_out,
    float* __restrict__ q_out,
    float* __restrict__ embed_sum,
    float* __restrict__ bins)
{
    __shared__ float xs[D];
    __shared__ float bv[256];
    __shared__ int   bidx[256];
    int cnt = *dirty_count;
    for (int i = blockIdx.x; i < cnt; i += gridDim.x) {
        int row = dirty_list[i];
        __syncthreads();
        if (threadIdx.x < D) xs[threadIdx.x] = x[(size_t)row * D + threadIdx.x];
        __syncthreads();
        float best = -3.4e38f;
        int   bi   = 0;
        int   c0   = threadIdx.x * 16;
        for (int c = c0; c < c0 + 16; ++c) {
            const float4* ep = (const float4*)(embed_n + (size_t)c * D);
            const float4* xp = (const float4*)xs;
            float a0 = 0.f, a1 = 0.f, a2 = 0.f, a3 = 0.f;
            #pragma unroll
            for (int k = 0; k < D / 4; ++k) {
                float4 e = ep[k], xx = xp[k];
                a0 = fmaf(e.x, xx.x, a0);
                a1 = fmaf(e.y, xx.y, a1);
                a2 = fmaf(e.z, xx.z, a2);
                a3 = fmaf(e.w, xx.w, a3);
            }
            float dd = (a0 + a1) + (a2 + a3);
            if (dd > best) { best = dd; bi = c; }
        }
        bv[threadIdx.x]   = best;
        bidx[threadIdx.x] = bi;
        __syncthreads();
        #pragma unroll
        for (int s = 128; s > 0; s >>= 1) {
            if (threadIdx.x < s) {
                float v2 = bv[threadIdx.x + s];
                int   i2 = bidx[threadIdx.x + s];
                if (v2 > bv[threadIdx.x] ||
                    (v2 == bv[threadIdx.x] && i2 < bidx[threadIdx.x])) {
                    bv[threadIdx.x]   = v2;
                    bidx[threadIdx.x] = i2;
                }
            }
            __syncthreads();
        }
        int fi = bidx[0];
        if (threadIdx.x == 0) {
            ind_out[row] = (float)fi;
            atomicAdd(&bins[fi], 1.0f);
        }
        if (threadIdx.x < 64) {
            float xk = xs[threadIdx.x];
            float ss = xk * xk;
            #pragma unroll
            for (int o = 32; o > 0; o >>= 1) ss += __shfl_xor(ss, o);
            float inv = 1.0f / fmaxf(sqrtf(ss), 1e-12f);
            q_out[(size_t)row * D + threadIdx.x] =
                embed[(size_t)fi * D + threadIdx.x];
            atomicAdd(&embed_sum[(size_t)fi * D + threadIdx.x], xk * inv);
        }
        __syncthreads();
    }
}

// ---------------------------------------------------------------------------
// Kernel 5: EMA finalize per code. One wave per code.
// ---------------------------------------------------------------------------
__global__ __launch_bounds__(256) void finalize_kernel(
    const float* __restrict__ embed,
    const float* __restrict__ cluster_size,
    const float* __restrict__ embed_n,
    const float* __restrict__ embed_sum,
    const float* __restrict__ bins,
    float* __restrict__ new_embed_out,
    float* __restrict__ new_cs_out)
{
    int code = blockIdx.x * 4 + (threadIdx.x >> 6);
    int lane = threadIdx.x & 63;
    float bsum = bins[code];
    if (lane == 0)
        new_cs_out[code] = cluster_size[code] * DECAY + bsum * (1.0f - DECAY);

    float en;
    if (bsum == 0.0f) {
        en = embed_n[code * D + lane];
    } else {
        float v = embed_sum[code * D + lane] / bsum;
        float ss = v * v;
        #pragma unroll
        for (int o = 32; o > 0; o >>= 1) ss += __shfl_xor(ss, o);
        en = v / fmaxf(sqrtf(ss), 1e-12f);
    }
    new_embed_out[code * D + lane] =
        embed[code * D + lane] * DECAY + en * (1.0f - DECAY);
}

// ---------------------------------------------------------------------------
extern "C" void kernel_launch(void* const* d_in, const int* in_sizes, int n_in,
                              void* d_out, int out_size, void* d_ws, size_t ws_size,
                              hipStream_t stream)
{
    const float* x            = (const float*)d_in[0];
    const float* embed        = (const float*)d_in[1];
    const float* cluster_size = (const float*)d_in[2];

    float* out     = (float*)d_out;
    float* q_out   = out;                          // N*D
    float* ind_out = out + (size_t)N * D;          // N
    float* ne_out  = ind_out + N;                  // C*D
    float* ncs_out = ne_out + (size_t)C * D;       // C

    char* ws = (char*)d_ws;
    float*          embed_n     = (float*)ws;                       // 1 MB
    float*          embed_sum   = (float*)(ws + (1u << 20));        // 1 MB
    float*          bins        = (float*)(ws + (2u << 20));        // 16 KB
    int*            dirty_list  = (int*)(ws + (2u << 20) + 65536);  // 256 KB
    int*            dirty_count = (int*)(ws + (2u << 20) + 65536 + 262144);
    unsigned short* e_hi        = (unsigned short*)(ws + 3 * (1u << 20));  // 512 KB
    unsigned short* e_lo        = (unsigned short*)(ws + 3 * (1u << 20) + 524288);

    prep_e_kernel<<<C / 4, 256, 0, stream>>>(embed, embed_n, e_hi, e_lo,
                                             embed_sum, bins, dirty_count);
    assign_mfma_kernel<<<dim3(N / 128, NCHUNK), 256, 0, stream>>>(
        x, e_hi, e_lo, q_out);
    merge_scatter_kernel<<<N / 4, 256, 0, stream>>>(x, embed, embed_n,
                                                    q_out, ind_out,
                                                    embed_sum, bins,
                                                    dirty_count, dirty_list);
    fallback_kernel<<<1024, 256, 0, stream>>>(x, embed, embed_n, dirty_count,
                                              dirty_list, ind_out, q_out,
                                              embed_sum, bins);
    finalize_kernel<<<C / 4, 256, 0, stream>>>(embed, cluster_size, embed_n,
                                               embed_sum, bins, ne_out, ncs_out);
}